// Round 7
// baseline (148.682 us; speedup 1.0000x reference)
//
#include <hip/hip_runtime.h>
#include <hip/hip_fp16.h>

#define N_NODES 50000
#define N_EDGES 800000
// D_FEAT=64, D_EDGE=16, D_HID=16, D_MSG=64, D_OUT=64

#define NB  196    // coarse buckets (256 nodes each; 196*256 = 50176 >= 50000)
#define PB  256    // partition/chist blocks
#define EPB 3125   // edges per partition block (256*3125 = 800000 exact)
#define PITERS 13  // ceil(3125/256)
#define CAP 7680   // finesort LDS staging capacity (max bucket ~4.4k)

__device__ __forceinline__ unsigned fkey(float f) {
    unsigned u = __float_as_uint(f);
    return (u & 0x80000000u) ? ~u : (u | 0x80000000u);
}
#define KEY_NEG_INF 0x007FFFFFu  // key(-inf)

// wave-local LDS fence (per-wave private LDS region; DS pipe in-order per wave)
__device__ __forceinline__ void wave_lds_fence() {
    asm volatile("s_waitcnt lgkmcnt(0)" ::: "memory");
    __builtin_amdgcn_sched_barrier(0);
}

// ---------------- chist + xw: coarse hist of dst>>8, plus xw precompute ----
// xw[v][k] = b1[k] + sum_i x[v][i] * W1[(16+i)*16 + k]
__global__ __launch_bounds__(256) void chist_xw_kernel(
    const int* __restrict__ dst, unsigned* __restrict__ bcnt,
    const float* __restrict__ x, const float* __restrict__ W1,
    const float* __restrict__ b1, float* __restrict__ xw)
{
    __shared__ unsigned lh[NB];
    const int t = threadIdx.x, b = blockIdx.x;
    if (t < NB) lh[t] = 0u;
    __syncthreads();
    const int e0 = b * EPB;
#pragma unroll
    for (int it = 0; it < PITERS; ++it) {
        const int i = it * 256 + t;
        if (i < EPB) atomicAdd(&lh[(unsigned)dst[e0 + i] >> 8], 1u);
    }
    __syncthreads();
    if (t < NB) bcnt[b * NB + t] = lh[t];

    // xw for node v = b*256+t (blocks 0..195 cover 50176 >= 50000)
    if (b < 196) {
        const int v = b * 256 + t;
        if (v < N_NODES) {
            float acc[16];
#pragma unroll
            for (int k = 0; k < 16; ++k) acc[k] = b1[k];
            const float4* xp = reinterpret_cast<const float4*>(x) + (size_t)v * 16;
#pragma unroll
            for (int c = 0; c < 16; ++c) {
                float4 tv = xp[c];
                const float xv[4] = {tv.x, tv.y, tv.z, tv.w};
#pragma unroll
                for (int q = 0; q < 4; ++q) {
                    const int row = 16 + 4 * c + q;
#pragma unroll
                    for (int k = 0; k < 16; ++k)
                        acc[k] = fmaf(xv[q], W1[row * 16 + k], acc[k]);
                }
            }
            float4* op = reinterpret_cast<float4*>(xw) + (size_t)v * 4;
#pragma unroll
            for (int c = 0; c < 4; ++c) {
                float4 o; o.x = acc[4*c]; o.y = acc[4*c+1]; o.z = acc[4*c+2]; o.w = acc[4*c+3];
                op[c] = o;
            }
        }
    }
}

// ---------------- cscan: per-(block,bucket) deterministic offsets ----------
__global__ __launch_bounds__(256) void cscan_kernel(const unsigned* __restrict__ bcnt,
                                                    unsigned* __restrict__ gstart,
                                                    unsigned* __restrict__ boffG,
                                                    unsigned* __restrict__ totG) {
    __shared__ unsigned wsum[4];
    const int t = threadIdx.x, lane = t & 63, w = t >> 6;
    unsigned tot = 0;
    if (t < NB)
        for (int k = 0; k < PB; ++k) tot += bcnt[k * NB + t];
    unsigned v = (t < NB) ? tot : 0u;
    const unsigned orig = v;
#pragma unroll
    for (int d = 1; d < 64; d <<= 1) {
        unsigned n = __shfl_up(v, d, 64);
        if (lane >= d) v += n;
    }
    if (lane == 63) wsum[w] = v;
    __syncthreads();
    unsigned woff = 0;
#pragma unroll
    for (int i = 0; i < 3; ++i) if (i < w) woff += wsum[i];
    const unsigned boff = woff + v - orig;
    if (t < NB) {
        boffG[t] = boff;
        totG[t]  = tot;
        unsigned run = boff;
        for (int k = 0; k < PB; ++k) { gstart[k * NB + t] = run; run += bcnt[k * NB + t]; }
    }
}

// ---------------- hcomp: h16[e] = fp16(relu(xw[src[e]] + ef[e]@W1[:16])) ----
// Original edge order: ef read fully coalesced. Also fills rkey (same grid).
__global__ __launch_bounds__(256) void hcomp_kernel(
    const float* __restrict__ ef, const int* __restrict__ src,
    const float* __restrict__ xw, const float* __restrict__ W1,
    unsigned* __restrict__ rkey, unsigned* __restrict__ h16)
{
    const int e = blockIdx.x * 256 + threadIdx.x;  // 3125*256 = 800000 exact
    reinterpret_cast<uint4*>(rkey)[e] =
        make_uint4(KEY_NEG_INF, KEY_NEG_INF, KEY_NEG_INF, KEY_NEG_INF);

    float in[16];
    const float4* efp = reinterpret_cast<const float4*>(ef) + (size_t)e * 4;
#pragma unroll
    for (int c = 0; c < 4; ++c) {
        float4 tv = efp[c];
        in[4*c+0]=tv.x; in[4*c+1]=tv.y; in[4*c+2]=tv.z; in[4*c+3]=tv.w;
    }
    const int s = src[e];
    float h[16];
    const float4* xp = reinterpret_cast<const float4*>(xw) + (size_t)s * 4;
#pragma unroll
    for (int c = 0; c < 4; ++c) {
        float4 tv = xp[c];
        h[4*c+0]=tv.x; h[4*c+1]=tv.y; h[4*c+2]=tv.z; h[4*c+3]=tv.w;
    }
#pragma unroll
    for (int i = 0; i < 16; ++i)
#pragma unroll
        for (int k = 0; k < 16; ++k)
            h[k] = fmaf(in[i], W1[i*16 + k], h[k]);
    unsigned wds[8];
#pragma unroll
    for (int k = 0; k < 8; ++k) {
        __half2 t2 = __floats2half2_rn(fmaxf(h[2*k], 0.0f), fmaxf(h[2*k+1], 0.0f));
        wds[k] = *reinterpret_cast<unsigned*>(&t2);
    }
    uint4* hp = reinterpret_cast<uint4*>(h16) + (size_t)e * 2;
    hp[0] = make_uint4(wds[0], wds[1], wds[2], wds[3]);
    hp[1] = make_uint4(wds[4], wds[5], wds[6], wds[7]);
}

// ---------------- partition: LDS-staged coarse binning, coalesced flush ----
__global__ __launch_bounds__(256) void partition_kernel(const int* __restrict__ dst,
                                                        const unsigned* __restrict__ gstart,
                                                        unsigned long long* __restrict__ part) {
    __shared__ unsigned long long st[EPB];      // 25 KB
    __shared__ unsigned lh[NB], lstart[NB], lc[NB], gs[NB];
    __shared__ unsigned wsum[4];
    const int t = threadIdx.x, b = blockIdx.x, lane = t & 63, w = t >> 6;
    if (t < NB) { lh[t] = 0u; gs[t] = gstart[b * NB + t]; }
    __syncthreads();
    const int e0 = b * EPB;
#pragma unroll
    for (int it = 0; it < PITERS; ++it) {
        const int i = it * 256 + t;
        if (i < EPB) atomicAdd(&lh[(unsigned)dst[e0 + i] >> 8], 1u);
    }
    __syncthreads();
    {
        unsigned v = (t < NB) ? lh[t] : 0u;
        const unsigned orig = v;
#pragma unroll
        for (int d = 1; d < 64; d <<= 1) {
            unsigned n = __shfl_up(v, d, 64);
            if (lane >= d) v += n;
        }
        if (lane == 63) wsum[w] = v;
        __syncthreads();
        unsigned woff = 0;
#pragma unroll
        for (int i = 0; i < 3; ++i) if (i < w) woff += wsum[i];
        if (t < NB) { lstart[t] = woff + v - orig; lc[t] = woff + v - orig; }
    }
    __syncthreads();
#pragma unroll
    for (int it = 0; it < PITERS; ++it) {
        const int i = it * 256 + t;
        if (i < EPB) {
            const int e = e0 + i;
            const unsigned d = (unsigned)dst[e];
            const unsigned p = atomicAdd(&lc[d >> 8], 1u);
            st[p] = ((unsigned long long)d << 32) | (unsigned)e;
        }
    }
    __syncthreads();
#pragma unroll
    for (int it = 0; it < PITERS; ++it) {
        const int i = it * 256 + t;
        if (i < EPB) {
            const unsigned long long pv = st[i];
            const unsigned bkt = (unsigned)(pv >> 40);
            part[gs[bkt] + ((unsigned)i - lstart[bkt])] = pv;
        }
    }
}

// ---------------- finesort: sort one coarse bucket by exact dst ------------
__global__ __launch_bounds__(256) void finesort_kernel(const unsigned long long* __restrict__ part,
                                                       const unsigned* __restrict__ boffG,
                                                       const unsigned* __restrict__ totG,
                                                       unsigned long long* __restrict__ dsf) {
    __shared__ unsigned long long st[CAP];      // 60 KB
    __shared__ unsigned fh[256], fstart[256];
    __shared__ unsigned wsum[4];
    const int t = threadIdx.x, b = blockIdx.x, lane = t & 63, w = t >> 6;
    const unsigned base = boffG[b], cnt = totG[b];
    fh[t] = 0u;
    __syncthreads();
    const int iters = (int)((cnt + 255u) >> 8);
    for (int it = 0; it < iters; ++it) {
        const unsigned i = (unsigned)it * 256u + (unsigned)t;
        if (i < cnt) atomicAdd(&fh[(unsigned)(part[base + i] >> 32) & 255u], 1u);
    }
    __syncthreads();
    {
        unsigned v = fh[t];
        const unsigned orig = v;
#pragma unroll
        for (int d = 1; d < 64; d <<= 1) {
            unsigned n = __shfl_up(v, d, 64);
            if (lane >= d) v += n;
        }
        if (lane == 63) wsum[w] = v;
        __syncthreads();
        unsigned woff = 0;
#pragma unroll
        for (int i = 0; i < 3; ++i) if (i < w) woff += wsum[i];
        fstart[t] = woff + v - orig;
    }
    __syncthreads();
    if (cnt <= CAP) {
        for (int it = 0; it < iters; ++it) {
            const unsigned i = (unsigned)it * 256u + (unsigned)t;
            if (i < cnt) {
                const unsigned long long pv = part[base + i];
                const unsigned p = atomicAdd(&fstart[(unsigned)(pv >> 32) & 255u], 1u);
                st[p] = pv;
            }
        }
        __syncthreads();
        for (int it = 0; it < iters; ++it) {
            const unsigned i = (unsigned)it * 256u + (unsigned)t;
            if (i < cnt) dsf[base + i] = st[i];
        }
    } else {
        for (int it = 0; it < iters; ++it) {
            const unsigned i = (unsigned)it * 256u + (unsigned)t;
            if (i < cnt) {
                const unsigned long long pv = part[base + i];
                const unsigned p = atomicAdd(&fstart[(unsigned)(pv >> 32) & 255u], 1u);
                dsf[base + p] = pv;
            }
        }
    }
}

// ---------------- init0: rkey fill only (tiers 2/3) ------------------------
__global__ __launch_bounds__(256) void init0_kernel(unsigned* __restrict__ rkey) {
    const int i = blockIdx.x * 256 + threadIdx.x;
    reinterpret_cast<uint4*>(rkey)[i] =
        make_uint4(KEY_NEG_INF, KEY_NEG_INF, KEY_NEG_INF, KEY_NEG_INF);
}

// ---------------- edge kernel tier-1: h16 gather + layer-2 + seg reduce ----
__global__ __launch_bounds__(256) void edge_h16_kernel(
    const unsigned* __restrict__ h16,
    const unsigned long long* __restrict__ ds,
    const float* __restrict__ W2, const float* __restrict__ b2,
    unsigned* __restrict__ rkey)
{
    const int lane = threadIdx.x & 63;
    const int w    = threadIdx.x >> 6;
    const int wave = blockIdx.x * 4 + w;
    const int base = wave * 64;
    const int slot = base + lane;

    __shared__ unsigned mld[4][64][17];
    __shared__ int      dldA[4][66];
    int* dld = &dldA[w][1];

    const unsigned long long pv = ds[slot];
    const int e = (int)(unsigned)pv;
    const int d = (int)(pv >> 32);
    dld[lane] = d;
    if (lane == 0)  dld[-1] = (base == 0) ? -1 : (int)(ds[base - 1] >> 32);
    if (lane == 63) dld[64] = (base + 64 >= N_EDGES) ? -1 : (int)(ds[base + 64] >> 32);

    // ---- gather h (32 B random from 25.6 MB) ----
    float h[16];
    {
        const uint4* hp = reinterpret_cast<const uint4*>(h16) + (size_t)e * 2;
        uint4 A = hp[0], B = hp[1];
        unsigned wd[8] = {A.x, A.y, A.z, A.w, B.x, B.y, B.z, B.w};
#pragma unroll
        for (int k = 0; k < 8; ++k) {
            __half2 t2 = *reinterpret_cast<const __half2*>(&wd[k]);
            float2 f = __half22float2(t2);
            h[2*k] = f.x; h[2*k+1] = f.y;
        }
    }

    const int q  = lane >> 4;
    const int jj = lane & 15;

#pragma unroll
    for (int j0 = 0; j0 < 64; j0 += 16) {
        float m[16];
#pragma unroll
        for (int t = 0; t < 16; ++t) m[t] = b2[j0 + t];
#pragma unroll
        for (int k = 0; k < 16; ++k)
#pragma unroll
            for (int t = 0; t < 16; ++t)
                m[t] = fmaf(h[k], W2[k*64 + j0 + t], m[t]);

        wave_lds_fence();
#pragma unroll
        for (int t = 0; t < 16; ++t) mld[w][lane][t] = fkey(m[t]);
        wave_lds_fence();

        const int s0 = q * 16;
        unsigned run = KEY_NEG_INF;
        int  dprev = dld[s0 - 1];
        bool phead = (dld[s0] != dprev);
        dprev = dld[s0];
        run = mld[w][s0][jj];
#pragma unroll
        for (int i = 1; i < 16; ++i) {
            const int ss = s0 + i;
            const int dsv = dld[ss];
            if (dsv != dprev) {
                unsigned* addr = &rkey[((size_t)dprev << 6) + (unsigned)(j0 + jj)];
                if (phead) *addr = run;
                else       atomicMax(addr, run);
                run = KEY_NEG_INF;
                phead = true;
            }
            run = max(run, mld[w][ss][jj]);
            dprev = dsv;
        }
        const bool ptail = (dld[s0 + 16] != dprev);
        unsigned* addr = &rkey[((size_t)dprev << 6) + (unsigned)(j0 + jj)];
        if (phead && ptail) *addr = run;
        else                atomicMax(addr, run);
    }
}

// ---------------- edge kernel tier-2 (round-6 path: xw/ef/src gathers) -----
__global__ __launch_bounds__(256) void edge_csr2_kernel(
    const float* __restrict__ xw, const float* __restrict__ ef,
    const int* __restrict__ src,
    const unsigned long long* __restrict__ ds,
    const float* __restrict__ W1, const float* __restrict__ W2,
    const float* __restrict__ b2,
    unsigned* __restrict__ rkey)
{
    const int lane = threadIdx.x & 63;
    const int w    = threadIdx.x >> 6;
    const int wave = blockIdx.x * 4 + w;
    const int base = wave * 64;
    const int slot = base + lane;

    __shared__ unsigned mld[4][64][17];
    __shared__ int      dldA[4][66];
    int* dld = &dldA[w][1];

    const unsigned long long pv = ds[slot];
    const int e = (int)(unsigned)pv;
    const int d = (int)(pv >> 32);
    dld[lane] = d;
    if (lane == 0)  dld[-1] = (base == 0) ? -1 : (int)(ds[base - 1] >> 32);
    if (lane == 63) dld[64] = (base + 64 >= N_EDGES) ? -1 : (int)(ds[base + 64] >> 32);

    float in[16];
    const float4* efp = reinterpret_cast<const float4*>(ef) + (size_t)e * 4;
#pragma unroll
    for (int c = 0; c < 4; ++c) {
        float4 tv = efp[c];
        in[4*c+0]=tv.x; in[4*c+1]=tv.y; in[4*c+2]=tv.z; in[4*c+3]=tv.w;
    }
    const int s = src[e];
    float h[16];
    const float4* xp = reinterpret_cast<const float4*>(xw) + (size_t)s * 4;
#pragma unroll
    for (int c = 0; c < 4; ++c) {
        float4 tv = xp[c];
        h[4*c+0]=tv.x; h[4*c+1]=tv.y; h[4*c+2]=tv.z; h[4*c+3]=tv.w;
    }
#pragma unroll
    for (int i = 0; i < 16; ++i)
#pragma unroll
        for (int k = 0; k < 16; ++k)
            h[k] = fmaf(in[i], W1[i*16 + k], h[k]);
#pragma unroll
    for (int k = 0; k < 16; ++k) h[k] = fmaxf(h[k], 0.0f);

    const int q  = lane >> 4;
    const int jj = lane & 15;

#pragma unroll
    for (int j0 = 0; j0 < 64; j0 += 16) {
        float m[16];
#pragma unroll
        for (int t = 0; t < 16; ++t) m[t] = b2[j0 + t];
#pragma unroll
        for (int k = 0; k < 16; ++k)
#pragma unroll
            for (int t = 0; t < 16; ++t)
                m[t] = fmaf(h[k], W2[k*64 + j0 + t], m[t]);

        wave_lds_fence();
#pragma unroll
        for (int t = 0; t < 16; ++t) mld[w][lane][t] = fkey(m[t]);
        wave_lds_fence();

        const int s0 = q * 16;
        unsigned run = KEY_NEG_INF;
        int  dprev = dld[s0 - 1];
        bool phead = (dld[s0] != dprev);
        dprev = dld[s0];
        run = mld[w][s0][jj];
#pragma unroll
        for (int i = 1; i < 16; ++i) {
            const int ss = s0 + i;
            const int dsv = dld[ss];
            if (dsv != dprev) {
                unsigned* addr = &rkey[((size_t)dprev << 6) + (unsigned)(j0 + jj)];
                if (phead) *addr = run;
                else       atomicMax(addr, run);
                run = KEY_NEG_INF;
                phead = true;
            }
            run = max(run, mld[w][ss][jj]);
            dprev = dsv;
        }
        const bool ptail = (dld[s0 + 16] != dprev);
        unsigned* addr = &rkey[((size_t)dprev << 6) + (unsigned)(j0 + jj)];
        if (phead && ptail) *addr = run;
        else                atomicMax(addr, run);
    }
}

// ---------------- node kernel: decode + update MLP ----------------
// rkey and out alias (both d_out); each thread reads its row before writing it.
__global__ __launch_bounds__(256) void node_kernel(
    const float* __restrict__ x, const unsigned* rkey,
    const float* __restrict__ W1, const float* __restrict__ b1,
    const float* __restrict__ W2, const float* __restrict__ b2,
    float* out)
{
    const int v = blockIdx.x * 256 + threadIdx.x;
    if (v >= N_NODES) return;

    float in[128];
    const float4* xp = reinterpret_cast<const float4*>(x) + (size_t)v * 16;
#pragma unroll
    for (int c = 0; c < 16; ++c) {
        float4 tv = xp[c];
        in[4*c+0]=tv.x; in[4*c+1]=tv.y; in[4*c+2]=tv.z; in[4*c+3]=tv.w;
    }
    const uint4* rp = reinterpret_cast<const uint4*>(rkey) + (size_t)v * 16;
#pragma unroll
    for (int c = 0; c < 16; ++c) {
        uint4 tv = rp[c];
        unsigned ks[4] = {tv.x, tv.y, tv.z, tv.w};
#pragma unroll
        for (int qq = 0; qq < 4; ++qq) {
            unsigned k = ks[qq];
            unsigned u = (k & 0x80000000u) ? (k ^ 0x80000000u) : ~k;
            float f = __uint_as_float(u);
            if (!(f >= -3.402823466e38f && f <= 3.402823466e38f)) f = 0.0f;
            in[64 + 4*c + qq] = f;
        }
    }

    float h[16];
#pragma unroll
    for (int k = 0; k < 16; ++k) h[k] = b1[k];
#pragma unroll
    for (int i = 0; i < 128; ++i)
#pragma unroll
        for (int k = 0; k < 16; ++k)
            h[k] = fmaf(in[i], W1[i*16 + k], h[k]);
#pragma unroll
    for (int k = 0; k < 16; ++k) h[k] = fmaxf(h[k], 0.0f);

    float* op = out + (size_t)v * 64;
#pragma unroll
    for (int c = 0; c < 16; ++c) {
        float oo[4];
#pragma unroll
        for (int qq = 0; qq < 4; ++qq) {
            float a = b2[4*c + qq];
#pragma unroll
            for (int k = 0; k < 16; ++k)
                a = fmaf(h[k], W2[k*64 + 4*c + qq], a);
            oo[qq] = a;
        }
        float4 o; o.x=oo[0]; o.y=oo[1]; o.z=oo[2]; o.w=oo[3];
        reinterpret_cast<float4*>(op)[c] = o;
    }
}

// ---------------- tier-3 fallback edge kernel (direct atomics) -------------
__global__ __launch_bounds__(64) void edge_kernel(
    const float* __restrict__ x, const float* __restrict__ ef,
    const int* __restrict__ src, const int* __restrict__ dst,
    const float* __restrict__ W1, const float* __restrict__ b1,
    const float* __restrict__ W2, const float* __restrict__ b2,
    unsigned* __restrict__ rkey)
{
    const int lane = threadIdx.x;
    const int e    = blockIdx.x * 64 + lane;

    __shared__ unsigned mld[64][17];
    __shared__ int      dld[64];

    float in[80];
    const float4* efp = reinterpret_cast<const float4*>(ef) + (size_t)e * 4;
#pragma unroll
    for (int c = 0; c < 4; ++c) {
        float4 tv = efp[c];
        in[4*c+0]=tv.x; in[4*c+1]=tv.y; in[4*c+2]=tv.z; in[4*c+3]=tv.w;
    }
    const int s = src[e];
    dld[lane] = dst[e];
    const float4* xp = reinterpret_cast<const float4*>(x) + (size_t)s * 16;
#pragma unroll
    for (int c = 0; c < 16; ++c) {
        float4 tv = xp[c];
        in[16+4*c+0]=tv.x; in[16+4*c+1]=tv.y; in[16+4*c+2]=tv.z; in[16+4*c+3]=tv.w;
    }

    float h[16];
#pragma unroll
    for (int k = 0; k < 16; ++k) h[k] = b1[k];
#pragma unroll
    for (int i = 0; i < 80; ++i)
#pragma unroll
        for (int k = 0; k < 16; ++k)
            h[k] = fmaf(in[i], W1[i*16 + k], h[k]);
#pragma unroll
    for (int k = 0; k < 16; ++k) h[k] = fmaxf(h[k], 0.0f);

    const int er = lane >> 4;
    const int jj = lane & 15;

#pragma unroll
    for (int j0 = 0; j0 < 64; j0 += 16) {
        float m[16];
#pragma unroll
        for (int t = 0; t < 16; ++t) m[t] = b2[j0 + t];
#pragma unroll
        for (int k = 0; k < 16; ++k)
#pragma unroll
            for (int t = 0; t < 16; ++t)
                m[t] = fmaf(h[k], W2[k*64 + j0 + t], m[t]);

        wave_lds_fence();
#pragma unroll
        for (int t = 0; t < 16; ++t) mld[lane][t] = fkey(m[t]);
        wave_lds_fence();

#pragma unroll
        for (int eg = 0; eg < 16; ++eg) {
            const int ee = (eg << 2) | er;
            atomicMax(&rkey[((size_t)dld[ee] << 6) + (unsigned)(j0 + jj)],
                      mld[ee][jj]);
        }
    }
}

extern "C" void kernel_launch(void* const* d_in, const int* in_sizes, int n_in,
                              void* d_out, int out_size, void* d_ws, size_t ws_size,
                              hipStream_t stream) {
    const float* x   = (const float*)d_in[0];
    const float* ef  = (const float*)d_in[1];
    const int*   src = (const int*)d_in[2];
    const int*   dst = (const int*)d_in[3];
    const float* mW1 = (const float*)d_in[4];
    const float* mb1 = (const float*)d_in[5];
    const float* mW2 = (const float*)d_in[6];
    const float* mb2 = (const float*)d_in[7];
    const float* uW1 = (const float*)d_in[8];
    const float* ub1 = (const float*)d_in[9];
    const float* uW2 = (const float*)d_in[10];
    const float* ub2 = (const float*)d_in[11];

    unsigned* rkey = (unsigned*)d_out;  // 50000*64 u32 = 12.8 MB
    float*    out  = (float*)d_out;

    // ws layout (tier 1): dsf u64[E] | part u64[E] | bcnt u32[PB*NB] |
    //   gstart u32[PB*NB] | boffG u32[256] | totG u32[256] | xw f32[800000] |
    //   h16 u32[E*8]   (~42.1 MB)
    const size_t OFF_PART  = (size_t)N_EDGES;                 // u64 units
    unsigned long long* dsf  = (unsigned long long*)d_ws;
    unsigned long long* partW = dsf + OFF_PART;
    unsigned* bcnt   = (unsigned*)(partW + N_EDGES);
    unsigned* gstart = bcnt + (size_t)PB * NB;
    unsigned* boffG  = gstart + (size_t)PB * NB;
    unsigned* totG   = boffG + 256;
    float*    xw     = (float*)(totG + 256);
    unsigned* h16    = (unsigned*)(xw + N_EDGES);             // 800000 f32 = 50000*16 slot for xw

    const size_t T2_NEEDED = (size_t)((char*)h16 - (char*)d_ws) - (size_t)N_EDGES * 8; // without part (tier2 puts part in d_out)
    const size_t T1_NEEDED = (size_t)((char*)(h16 + (size_t)N_EDGES * 8) - (char*)d_ws);

    if (ws_size >= T1_NEEDED) {
        // tier 1: h16 pipeline; part in ws; rkey filled inside hcomp
        hipLaunchKernelGGL(chist_xw_kernel,  dim3(PB),   dim3(256), 0, stream, dst, bcnt, x, mW1, mb1, xw);
        hipLaunchKernelGGL(cscan_kernel,     dim3(1),    dim3(256), 0, stream, bcnt, gstart, boffG, totG);
        hipLaunchKernelGGL(hcomp_kernel,     dim3(3125), dim3(256), 0, stream, ef, src, xw, mW1, rkey, h16);
        hipLaunchKernelGGL(partition_kernel, dim3(PB),   dim3(256), 0, stream, dst, gstart, partW);
        hipLaunchKernelGGL(finesort_kernel,  dim3(NB),   dim3(256), 0, stream, partW, boffG, totG, dsf);
        hipLaunchKernelGGL(edge_h16_kernel,  dim3(3125), dim3(256), 0, stream, h16, dsf, mW2, mb2, rkey);
    } else if (ws_size >= T2_NEEDED) {
        // tier 2: round-6 path; part in d_out (dead before init0), xw gathers in edge
        unsigned long long* partO = (unsigned long long*)d_out;
        // re-pack ws without the part hole: dsf | bcnt | gstart | boffG | totG | xw
        unsigned* bcnt2   = (unsigned*)(dsf + N_EDGES);
        unsigned* gstart2 = bcnt2 + (size_t)PB * NB;
        unsigned* boffG2  = gstart2 + (size_t)PB * NB;
        unsigned* totG2   = boffG2 + 256;
        float*    xw2     = (float*)(totG2 + 256);
        hipLaunchKernelGGL(chist_xw_kernel,  dim3(PB),   dim3(256), 0, stream, dst, bcnt2, x, mW1, mb1, xw2);
        hipLaunchKernelGGL(cscan_kernel,     dim3(1),    dim3(256), 0, stream, bcnt2, gstart2, boffG2, totG2);
        hipLaunchKernelGGL(partition_kernel, dim3(PB),   dim3(256), 0, stream, dst, gstart2, partO);
        hipLaunchKernelGGL(finesort_kernel,  dim3(NB),   dim3(256), 0, stream, partO, boffG2, totG2, dsf);
        hipLaunchKernelGGL(init0_kernel,     dim3(3125), dim3(256), 0, stream, rkey);
        hipLaunchKernelGGL(edge_csr2_kernel, dim3(3125), dim3(256), 0, stream, xw2, ef, src, dsf, mW1, mW2, mb2, rkey);
    } else {
        // tier 3: direct atomics
        hipLaunchKernelGGL(init0_kernel, dim3(3125), dim3(256), 0, stream, rkey);
        hipLaunchKernelGGL(edge_kernel, dim3(12500), dim3(64), 0, stream,
                           x, ef, src, dst, mW1, mb1, mW2, mb2, rkey);
    }

    hipLaunchKernelGGL(node_kernel, dim3((N_NODES + 255) / 256), dim3(256), 0, stream,
                       x, rkey, uW1, ub1, uW2, ub2, out);
}